// Round 8
// baseline (2346.162 us; speedup 1.0000x reference)
//
#include <hip/hip_runtime.h>
#include <stdint.h>

// LSTM forward, B=128 T=512 F=256 H=512, Keras gate order i,f,g,o.
//  kernel lstm_xz : xz[B*T,2048] = x @ kernel + bias  (split-bf16 MFMA, fp16 output)
//  kernel lstm_rec: persistent scan. R8 = R6 + RAW BARRIER (the R7 lesson):
//    - R7 post-mortem: __syncthreads() emits s_waitcnt vmcnt(0) before s_barrier, so
//      anything issued between poll and barrier is a pure serial stall. R6's barrier
//      drained the fresh sentinel resets (~500cy) and its poll drained the pf loads
//      (~900cy) even when producers were ready.
//    - In-loop barrier is now s_waitcnt lgkmcnt(0) + raw s_barrier: LDS ordering only,
//      NO VMEM drain (the only in-loop correctness need is ds_write visibility).
//    - pf (xz prefetch) issued POST-poll: hides under GEMM+ew; never drained fresh.
//    - resets post-poll: drained at next poll ~2500cy later (complete, free).
//    - h-stores + out-stores at step end: drained at next poll while spinning on
//      producers; own-ack ~= peers' visibility (symmetric, unavoidable).
//    - Ping-pong WAR safety unchanged: ordering flows through the poll dataflow
//      (own-block columns in the staged tile), not the barrier.
// ws layout: [0, 256MB) xz fp16 | hbuf 8 groups x 4 slots x 16 rows x 256 dwords (512KB)

#define Bb 128
#define Tt 512
#define Ff 256
#define Hh 512
#define G4 2048
#define SENT 0xFFFFFFFFu

typedef __attribute__((ext_vector_type(8))) short short8;
typedef __attribute__((ext_vector_type(4))) float floatx4;
typedef __attribute__((ext_vector_type(4))) unsigned int uint4v;

__device__ __forceinline__ unsigned short f2bf(float f) {
    unsigned u = __float_as_uint(f);
    return (unsigned short)((u + 0x7FFFu + ((u >> 16) & 1u)) >> 16);
}
__device__ __forceinline__ float bf2f(unsigned short h) {
    return __uint_as_float(((unsigned)h) << 16);
}
__device__ __forceinline__ float sigm(float x) { return 1.f / (1.f + __expf(-x)); }
__device__ __forceinline__ float tanh_f(float x) {
    float e = __expf(-2.f * fabsf(x));
    return copysignf((1.f - e) / (1.f + e), x);
}

// ---------------------------------------------------------------------------
// Kernel A: xz = x @ w + bias, stored fp16. Split-bf16 (x=hi+lo) for accuracy.
// 128x128 tile / block, BK=32 (orig k), K=256. Grid 8192 blocks. (unchanged)
// ---------------------------------------------------------------------------
__global__ __launch_bounds__(256, 2) void lstm_xz(
    const float* __restrict__ x, const float* __restrict__ w,
    const float* __restrict__ bias, _Float16* __restrict__ xzh)
{
    __shared__ unsigned short Ahi[128 * 40];
    __shared__ unsigned short Alo[128 * 40];
    __shared__ unsigned short Wt [128 * 40];

    const int tid = threadIdx.x;
    int idx = blockIdx.x;
    int xcd = idx & 7;
    int chunk = idx >> 3;
    int msup = chunk >> 7;
    int s = chunk & 127;
    int nt = s >> 3;
    int mi0 = s & 7;
    int mt = xcd * 64 + msup * 8 + mi0;
    const int m0 = mt << 7;
    const int n0 = nt << 7;

    const int lane = tid & 63;
    const int wv = tid >> 6;
    const int wm = wv >> 1, wn = wv & 1;
    const int cB = lane & 15, kgrp = lane >> 4;

    floatx4 acc[4][4];
#pragma unroll
    for (int i = 0; i < 4; ++i)
#pragma unroll
        for (int j = 0; j < 4; ++j) acc[i][j] = (floatx4){0.f, 0.f, 0.f, 0.f};

    float bv[4];
#pragma unroll
    for (int ni = 0; ni < 4; ++ni) bv[ni] = bias[n0 + wn * 64 + ni * 16 + cB];

    for (int it = 0; it < 8; ++it) {
        const int k0 = it * 32;
#pragma unroll
        for (int sw = 0; sw < 4; ++sw) {
            int e = sw * 256 + tid;
            int row = e >> 3, kq = e & 7;
            float4 v = *((const float4*)(x + (size_t)(m0 + row) * Ff + k0) + kq);
            unsigned short h0 = f2bf(v.x), h1 = f2bf(v.y), h2 = f2bf(v.z), h3 = f2bf(v.w);
            unsigned short l0 = f2bf(v.x - bf2f(h0)), l1 = f2bf(v.y - bf2f(h1));
            unsigned short l2 = f2bf(v.z - bf2f(h2)), l3 = f2bf(v.w - bf2f(h3));
            uint2 ph, pl;
            ph.x = (unsigned)h0 | ((unsigned)h1 << 16); ph.y = (unsigned)h2 | ((unsigned)h3 << 16);
            pl.x = (unsigned)l0 | ((unsigned)l1 << 16); pl.y = (unsigned)l2 | ((unsigned)l3 << 16);
            *(uint2*)(&Ahi[row * 40 + kq * 4]) = ph;
            *(uint2*)(&Alo[row * 40 + kq * 4]) = pl;
        }
#pragma unroll
        for (int sw = 0; sw < 4; ++sw) {
            int e = sw * 256 + tid;
            int kr = e >> 5, nq = e & 31;
            float4 v = *((const float4*)(w + (size_t)(k0 + kr) * G4 + n0) + nq);
            int nb = nq * 4;
            Wt[(nb + 0) * 40 + kr] = f2bf(v.x);
            Wt[(nb + 1) * 40 + kr] = f2bf(v.y);
            Wt[(nb + 2) * 40 + kr] = f2bf(v.z);
            Wt[(nb + 3) * 40 + kr] = f2bf(v.w);
        }
        __syncthreads();

        short8 bfr[4];
#pragma unroll
        for (int ni = 0; ni < 4; ++ni)
            bfr[ni] = *(const short8*)(&Wt[(wn * 64 + ni * 16 + cB) * 40 + kgrp * 8]);
#pragma unroll
        for (int mi = 0; mi < 4; ++mi) {
            short8 ah = *(const short8*)(&Ahi[(wm * 64 + mi * 16 + cB) * 40 + kgrp * 8]);
            short8 al = *(const short8*)(&Alo[(wm * 64 + mi * 16 + cB) * 40 + kgrp * 8]);
#pragma unroll
            for (int ni = 0; ni < 4; ++ni) {
                acc[mi][ni] = __builtin_amdgcn_mfma_f32_16x16x32_bf16(ah, bfr[ni], acc[mi][ni], 0, 0, 0);
                acc[mi][ni] = __builtin_amdgcn_mfma_f32_16x16x32_bf16(al, bfr[ni], acc[mi][ni], 0, 0, 0);
            }
        }
        __syncthreads();
    }
#pragma unroll
    for (int mi = 0; mi < 4; ++mi)
#pragma unroll
        for (int ni = 0; ni < 4; ++ni) {
            int rowb = m0 + wm * 64 + mi * 16 + kgrp * 4;
            int col = n0 + wn * 64 + ni * 16 + cB;
#pragma unroll
            for (int rr = 0; rr < 4; ++rr)
                xzh[(size_t)(rowb + rr) * G4 + col] = (_Float16)(acc[mi][ni][rr] + bv[ni]);
        }
}

// ---------------------------------------------------------------------------
// Kernel R: persistent scan, 128 blocks = 8 row-groups x 16 col-blocks.
// Block: 256 thr / 4 waves; wave w owns h cols [cb*32 + w*8, +8) (x 4 gates = 32 n).
// B-frags in registers; h tile ping-pong staged in (reused) Rlds; raw barrier/step.
// ---------------------------------------------------------------------------
__global__ __launch_bounds__(256, 1) void lstm_rec(
    const _Float16* __restrict__ xzh, const float* __restrict__ rk,
    unsigned* __restrict__ hbuf_u, float* __restrict__ out)
{
    __shared__ unsigned short Rlds[128 * 512];   // 128 KB; rows 0-31 reused as h ping-pong

    const int tid = threadIdx.x;
    const int idx = blockIdx.x;
    const int rg = idx & 7;          // row group
    const int cb = idx >> 3;         // 0..15 col block
    const int b0 = rg * 16;
    const int hc0 = cb * 32;

    const int lane = tid & 63;
    const int wv = tid >> 6;
    const int cB = lane & 15, kgrp = lane >> 4;
    const int hcw = hc0 + wv * 8;    // wave's 8 h cols
    const int c7 = cB & 7;
    const int col = hcw + c7;        // this lane's h col (duplicated in lane^8)
    const bool hi = (cB & 8) != 0;

    // ---- preload R slice into LDS, bf16, XOR-swizzled: elem (n,k) at k^((n&7)*8) ----
    for (int e = tid; e < 64 * 512; e += 256) {
        int p = e & 63, k = e >> 6;
        int n0 = 2 * p;
        int loc = n0 & 31, w = n0 >> 5;
        int gate = ((loc >> 4) << 1) | ((loc >> 3) & 1);
        int gcol = gate * Hh + hc0 + w * 8 + (loc & 7);
        float2 v = *(const float2*)(rk + (size_t)k * G4 + gcol);
        Rlds[n0 * 512 + (k ^ ((n0 & 7) << 3))] = f2bf(v.x);
        Rlds[(n0 + 1) * 512 + (k ^ (((n0 + 1) & 7) << 3))] = f2bf(v.y);
    }

    // per-row running xz pointers (4), gate offset is an immediate (g*1KB)
    const unsigned* xz_u = (const unsigned*)xzh;
    const unsigned* pr[4];
#pragma unroll
    for (int r = 0; r < 4; ++r)
        pr[r] = xz_u + ((size_t)(b0 + kgrp * 4 + r) * Tt * G4 + (col & ~1)) / 2;

    float xzr[16];                            // [gate*4 + row]
#pragma unroll
    for (int g = 0; g < 4; ++g)
#pragma unroll
        for (int r = 0; r < 4; ++r) {
            unsigned v = pr[r][g * 256];
            xzr[g * 4 + r] = (float)__builtin_bit_cast(_Float16,
                (unsigned short)((col & 1) ? (v >> 16) : (v & 0xffffu)));
        }
#pragma unroll
    for (int r = 0; r < 4; ++r) pr[r] += G4 / 2;   // -> t=1

    __syncthreads();  // Rlds ready

    // ---- hoist B fragments to registers: 2 n-tiles x 16 kk = 128 VGPRs ----
    short8 bf0[16], bf1[16];
    {
        const int nb = wv * 32;
        const int swz = c7 << 3;
#pragma unroll
        for (int kk = 0; kk < 16; ++kk) {
            int kb = (kk * 32 + kgrp * 8) ^ swz;
            bf0[kk] = *(const short8*)&Rlds[(nb + cB) * 512 + kb];
            bf1[kk] = *(const short8*)&Rlds[(nb + 16 + cB) * 512 + kb];
        }
    }
    __syncthreads();  // hoist reads done; Rlds rows 0-31 now reusable as h buffers

    float creg[4] = {0.f, 0.f, 0.f, 0.f};
    unsigned* const gbase = hbuf_u + (size_t)rg * 4 * 4096;   // 4 slots x 16x256 dwords
    const bool ew = (!hi && !(cB & 1));

    for (int t = 0; t < Tt; ++t) {
        const bool last = (t == Tt - 1);

        floatx4 acc0 = (floatx4){0.f, 0.f, 0.f, 0.f};
        floatx4 acc1 = (floatx4){0.f, 0.f, 0.f, 0.f};
        unsigned pf[16];

        if (t > 0) {
            // ping-pong h buffer for this step (overlaid on Rlds rows 0-31)
            unsigned short* const hs = (t & 1) ? (Rlds + 16 * 512) : Rlds;
            unsigned* const hcu = (unsigned*)hs;

            // 1. poll+stage h(t-1) from slot (t-1)&3: wave stages rows wv+4s.
            //    Drain at entry: only last step's h/out stores (~500cy, overlaps
            //    the producer-wait spin anyway).
            {
                const unsigned* sb = gbase + ((t - 1) & 3) * 4096;
                const unsigned* q0 = sb + (wv + 0) * 256 + 4 * lane;
                const unsigned* q1 = sb + (wv + 4) * 256 + 4 * lane;
                const unsigned* q2 = sb + (wv + 8) * 256 + 4 * lane;
                const unsigned* q3 = sb + (wv + 12) * 256 + 4 * lane;
                uint4v v0, v1, v2, v3;
                asm volatile("global_load_dwordx4 %0, %1, off sc0 sc1" : "=v"(v0) : "v"(q0) : "memory");
                asm volatile("global_load_dwordx4 %0, %1, off sc0 sc1" : "=v"(v1) : "v"(q1) : "memory");
                asm volatile("global_load_dwordx4 %0, %1, off sc0 sc1" : "=v"(v2) : "v"(q2) : "memory");
                asm volatile("global_load_dwordx4 %0, %1, off sc0 sc1" : "=v"(v3) : "v"(q3) : "memory");
                asm volatile("s_waitcnt vmcnt(0)" ::: "memory");
                while (__any((v0[0] == SENT) | (v0[1] == SENT) | (v0[2] == SENT) | (v0[3] == SENT))) {
                    asm volatile("global_load_dwordx4 %0, %1, off sc0 sc1" : "=v"(v0) : "v"(q0) : "memory");
                    asm volatile("s_waitcnt vmcnt(0)" ::: "memory");
                }
                *(uint4v*)(hcu + (wv + 0) * 256 + 4 * (lane ^ ((wv + 0) & 7))) = v0;
                while (__any((v1[0] == SENT) | (v1[1] == SENT) | (v1[2] == SENT) | (v1[3] == SENT))) {
                    asm volatile("global_load_dwordx4 %0, %1, off sc0 sc1" : "=v"(v1) : "v"(q1) : "memory");
                    asm volatile("s_waitcnt vmcnt(0)" ::: "memory");
                }
                *(uint4v*)(hcu + (wv + 4) * 256 + 4 * (lane ^ ((wv + 4) & 7))) = v1;
                while (__any((v2[0] == SENT) | (v2[1] == SENT) | (v2[2] == SENT) | (v2[3] == SENT))) {
                    asm volatile("global_load_dwordx4 %0, %1, off sc0 sc1" : "=v"(v2) : "v"(q2) : "memory");
                    asm volatile("s_waitcnt vmcnt(0)" ::: "memory");
                }
                *(uint4v*)(hcu + (wv + 8) * 256 + 4 * (lane ^ ((wv + 8) & 7))) = v2;
                while (__any((v3[0] == SENT) | (v3[1] == SENT) | (v3[2] == SENT) | (v3[3] == SENT))) {
                    asm volatile("global_load_dwordx4 %0, %1, off sc0 sc1" : "=v"(v3) : "v"(q3) : "memory");
                    asm volatile("s_waitcnt vmcnt(0)" ::: "memory");
                }
                *(uint4v*)(hcu + (wv + 12) * 256 + 4 * (lane ^ ((wv + 12) & 7))) = v3;
            }

            // 2. xz prefetch (POST-poll): raw barrier below does NOT drain it; it
            //    retires during GEMM+ew, consumed at step end (~1500cy later).
            if (!last) {
#pragma unroll
                for (int g = 0; g < 4; ++g)
#pragma unroll
                    for (int r = 0; r < 4; ++r)
                        pf[g * 4 + r] = pr[r][g * 256];
            }

            // 3. recycle slot (t-2): fire-and-forget; drained by next poll's
            //    vmcnt(0) (~2500cy later), before h(t+1) signal. No barrier drain.
            if (t >= 2) {
                unsigned* rs = gbase + ((t - 2) & 3) * 4096
                             + (tid >> 4) * 256 + (hc0 >> 1) + (tid & 15);
                __hip_atomic_store(rs, SENT, __ATOMIC_RELAXED, __HIP_MEMORY_SCOPE_AGENT);
            }

            // 4. RAW barrier: LDS ordering only (ds_writes visible), no VMEM drain.
            asm volatile("s_waitcnt lgkmcnt(0)" ::: "memory");
            __builtin_amdgcn_sched_barrier(0);
            __builtin_amdgcn_s_barrier();
            __builtin_amdgcn_sched_barrier(0);

            // 5. GEMM: 16 ds_read_b128 (A) + 32 MFMA, B in registers.
            floatx4 e0 = (floatx4){0.f, 0.f, 0.f, 0.f};
            floatx4 e1 = (floatx4){0.f, 0.f, 0.f, 0.f};
            const int swz = c7 << 3;
#pragma unroll
            for (int kk = 0; kk < 16; kk += 2) {
                int kb0 = (kk * 32 + kgrp * 8) ^ swz;
                int kb1 = ((kk + 1) * 32 + kgrp * 8) ^ swz;
                short8 a0 = *(const short8*)&hs[cB * 512 + kb0];
                short8 a1 = *(const short8*)&hs[cB * 512 + kb1];
                acc0 = __builtin_amdgcn_mfma_f32_16x16x32_bf16(a0, bf0[kk], acc0, 0, 0, 0);
                acc1 = __builtin_amdgcn_mfma_f32_16x16x32_bf16(a0, bf1[kk], acc1, 0, 0, 0);
                e0 = __builtin_amdgcn_mfma_f32_16x16x32_bf16(a1, bf0[kk + 1], e0, 0, 0, 0);
                e1 = __builtin_amdgcn_mfma_f32_16x16x32_bf16(a1, bf1[kk + 1], e1, 0, 0, 0);
            }
            acc0 = acc0 + e0;
            acc1 = acc1 + e1;
        } else {
            // t==0: h = 0 -> z = xz only; just issue pf for t=1
#pragma unroll
            for (int g = 0; g < 4; ++g)
#pragma unroll
                for (int r = 0; r < 4; ++r)
                    pf[g * 4 + r] = pr[r][g * 256];
        }

        // 6. elementwise, in-register. C layout: col=lane&15, row=kgrp*4+reg.
        float hv[4];
#pragma unroll
        for (int r = 0; r < 4; ++r) {
            float a0 = acc0[r], a1 = acc1[r];
            float a0x = __shfl_xor(a0, 8);
            float a1x = __shfl_xor(a1, 8);
            float zi = (hi ? a0x : a0) + xzr[0 * 4 + r];
            float zf = (hi ? a0 : a0x) + xzr[1 * 4 + r];
            float zg = (hi ? a1x : a1) + xzr[2 * 4 + r];
            float zo = (hi ? a1 : a1x) + xzr[3 * 4 + r];
            creg[r] = sigm(zf) * creg[r] + sigm(zi) * tanh_f(zg);
            hv[r] = sigm(zo) * tanh_f(creg[r]);
        }

        float hn[4];
#pragma unroll
        for (int r = 0; r < 4; ++r) hn[r] = __shfl_xor(hv[r], 1);

        if (!last) {
            // 7. h exchange first (critical path), then out stores; both drained by
            //    the NEXT poll's vmcnt(0), overlapping the producer-wait spin.
            unsigned* wbase = gbase + (t & 3) * 4096;
#pragma unroll
            for (int r = 0; r < 4; ++r) {
                if (ew) {
                    unsigned hp = (unsigned)f2bf(hv[r]) | ((unsigned)f2bf(hn[r]) << 16);
                    __hip_atomic_store(wbase + (kgrp * 4 + r) * 256 + (col >> 1), hp,
                                       __ATOMIC_RELAXED, __HIP_MEMORY_SCOPE_AGENT);
                }
            }
#pragma unroll
            for (int r = 0; r < 4; ++r) {
                if (ew) {
                    size_t b = (size_t)(b0 + kgrp * 4 + r);
                    *(float2*)(out + (b * Tt + (size_t)t) * Hh + col) = make_float2(hv[r], hn[r]);
                }
            }
        }

        if (last) {
            float* hl = out + (size_t)Bb * Tt * Hh;
            float* cl = hl + (size_t)Bb * Hh;
#pragma unroll
            for (int r = 0; r < 4; ++r) {
                float cn = __shfl_xor(creg[r], 1);
                if (ew) {
                    size_t b = (size_t)(b0 + kgrp * 4 + r);
                    *(float2*)(out + (b * Tt + (size_t)t) * Hh + col) = make_float2(hv[r], hn[r]);
                    *(float2*)(hl + b * Hh + col) = make_float2(hv[r], hn[r]);
                    *(float2*)(cl + b * Hh + col) = make_float2(creg[r], cn);
                }
            }
            break;
        }

        // 8. consume prefetched xz; advance row pointers. No barrier here (ping-pong).
#pragma unroll
        for (int i = 0; i < 16; ++i)
            xzr[i] = (float)__builtin_bit_cast(_Float16,
                (unsigned short)((col & 1) ? (pf[i] >> 16) : (pf[i] & 0xffffu)));
#pragma unroll
        for (int r = 0; r < 4; ++r) pr[r] += G4 / 2;
    }
}

// ---------------------------------------------------------------------------
extern "C" void kernel_launch(void* const* d_in, const int* in_sizes, int n_in,
                              void* d_out, int out_size, void* d_ws, size_t ws_size,
                              hipStream_t stream) {
    (void)in_sizes; (void)n_in; (void)out_size; (void)ws_size;
    const float* x    = (const float*)d_in[0];
    const float* w    = (const float*)d_in[1];
    const float* rk   = (const float*)d_in[2];
    const float* bias = (const float*)d_in[3];
    float* out = (float*)d_out;

    char* ws = (char*)d_ws;
    const size_t XZ_BYTES   = (size_t)Bb * Tt * G4 * sizeof(_Float16);      // 268,435,456
    const size_t HBUF_BYTES = (size_t)8 * 4 * 16 * 256 * 4;                 // 524,288

    _Float16* xzh = (_Float16*)ws;
    unsigned* hbuf = (unsigned*)(ws + XZ_BYTES);

    // sentinel-init all slots (0xFF bytes -> 0xFFFFFFFF dwords)
    hipMemsetAsync(ws + XZ_BYTES, 0xFF, HBUF_BYTES, stream);

    lstm_xz<<<dim3(8192), dim3(256), 0, stream>>>(x, w, bias, xzh);
    lstm_rec<<<dim3(128), dim3(256), 0, stream>>>(xzh, rk, hbuf, out);
}

// Round 9
// 2068.882 us; speedup vs baseline: 1.1340x; 1.1340x over previous
//
#include <hip/hip_runtime.h>
#include <stdint.h>

// LSTM forward, B=128 T=512 F=256 H=512, Keras gate order i,f,g,o.
// R9: SINGLE persistent kernel. lstm_xz DELETED; the input projection is fused
// into the scan and computed in the poll-idle window.
//  - R7/R8 post-mortem: pf-pre-poll is the winning placement (VMEM in flight
//    before the poll completes for free during the producer spin). R6 structure
//    (syncthreads barrier, resets pre-barrier, stores at step end) restored verbatim.
//  - Per step, per wave: xz-GEMM (x(t)[16x256, split hi/lo] @ w-frags[regs], 32 MFMA)
//    issued BEFORE the poll -> fills the spin. h-GEMM (32 MFMA) after barrier as in R6.
//    ew: z = (xz_acc + h_acc)|selected + bias scalar.
//  - x(t+1): 4 float4 loads issued pre-poll (drain free in spin), convert+ds_write
//    pre-barrier into x ping-pong. w (256x128 bf16 hi) hoisted to 64 VGPR/wave in
//    preamble; bias: 4 scalars/lane.
//  - Removes: 256MB xz write + 256MB xz read + fp16 round-trip + 8192-block kernel.
// LDS: Rlds 128KB (preamble R/w staging; in-loop: h ping-pong 32KB @0, x ping-pong
//      2x(hi8KB+lo8KB) @16384 shorts).
// ws layout: hbuf 8 groups x 4 slots x 16 rows x 256 dwords (512KB), sentinel-init.

#define Bb 128
#define Tt 512
#define Ff 256
#define Hh 512
#define G4 2048
#define SENT 0xFFFFFFFFu
#define XB 16384   // x ping-pong base, in shorts

typedef __attribute__((ext_vector_type(8))) short short8;
typedef __attribute__((ext_vector_type(4))) float floatx4;
typedef __attribute__((ext_vector_type(4))) unsigned int uint4v;

__device__ __forceinline__ unsigned short f2bf(float f) {
    unsigned u = __float_as_uint(f);
    return (unsigned short)((u + 0x7FFFu + ((u >> 16) & 1u)) >> 16);
}
__device__ __forceinline__ float bf2f(unsigned short h) {
    return __uint_as_float(((unsigned)h) << 16);
}
__device__ __forceinline__ float sigm(float x) { return 1.f / (1.f + __expf(-x)); }
__device__ __forceinline__ float tanh_f(float x) {
    float e = __expf(-2.f * fabsf(x));
    return copysignf((1.f - e) / (1.f + e), x);
}

// convert 16 fp32 -> split bf16 hi/lo, write 2+2 swizzled 16B chunks
__device__ __forceinline__ void xconv_write(const float* xf, unsigned short* xd,
                                            int row, int kq) {
    unsigned short hs_[16], ls_[16];
#pragma unroll
    for (int j = 0; j < 16; ++j) {
        hs_[j] = f2bf(xf[j]);
        ls_[j] = f2bf(xf[j] - bf2f(hs_[j]));
    }
    uint4v h0, h1, l0, l1;
#pragma unroll
    for (int j = 0; j < 4; ++j) {
        h0[j] = (unsigned)hs_[2 * j]     | ((unsigned)hs_[2 * j + 1] << 16);
        h1[j] = (unsigned)hs_[8 + 2 * j] | ((unsigned)hs_[8 + 2 * j + 1] << 16);
        l0[j] = (unsigned)ls_[2 * j]     | ((unsigned)ls_[2 * j + 1] << 16);
        l1[j] = (unsigned)ls_[8 + 2 * j] | ((unsigned)ls_[8 + 2 * j + 1] << 16);
    }
    const int c0 = (kq * 2) ^ (row & 7);
    const int c1 = (kq * 2 + 1) ^ (row & 7);
    *(uint4v*)&xd[row * 256 + c0 * 8] = h0;
    *(uint4v*)&xd[row * 256 + c1 * 8] = h1;
    *(uint4v*)&xd[4096 + row * 256 + c0 * 8] = l0;
    *(uint4v*)&xd[4096 + row * 256 + c1 * 8] = l1;
}

// ---------------------------------------------------------------------------
// Persistent scan, 128 blocks = 8 row-groups x 16 col-blocks, 256 thr / 4 waves.
// Wave w owns h cols [cb*32 + w*8, +8) (x 4 gates = 32 n).
// ---------------------------------------------------------------------------
__global__ __launch_bounds__(256, 1) void lstm_rec(
    const float* __restrict__ x, const float* __restrict__ kern,
    const float* __restrict__ rk, const float* __restrict__ bias,
    unsigned* __restrict__ hbuf_u, float* __restrict__ out)
{
    __shared__ unsigned short Rlds[128 * 512];   // 128 KB

    const int tid = threadIdx.x;
    const int idx = blockIdx.x;
    const int rg = idx & 7;          // row group
    const int cb = idx >> 3;         // 0..15 col block
    const int b0 = rg * 16;
    const int hc0 = cb * 32;

    const int lane = tid & 63;
    const int wv = tid >> 6;
    const int cB = lane & 15, kgrp = lane >> 4;
    const int c7 = cB & 7;
    const int col = hc0 + wv * 8 + c7;   // lane's h col (duplicated in lane^8)
    const bool hi = (cB & 8) != 0;
    const int xrow = tid >> 4, xkq = tid & 15;   // x staging assignment

    // ---- preload R slice [n=128][k=512] bf16, swizzled ----
    for (int e = tid; e < 64 * 512; e += 256) {
        int p = e & 63, k = e >> 6;
        int n0 = 2 * p;
        int loc = n0 & 31, w = n0 >> 5;
        int gate = ((loc >> 4) << 1) | ((loc >> 3) & 1);
        int gcol = gate * Hh + hc0 + w * 8 + (loc & 7);
        float2 v = *(const float2*)(rk + (size_t)k * G4 + gcol);
        Rlds[n0 * 512 + (k ^ ((n0 & 7) << 3))] = f2bf(v.x);
        Rlds[(n0 + 1) * 512 + (k ^ (((n0 + 1) & 7) << 3))] = f2bf(v.y);
    }
    __syncthreads();
    // hoist R fragments: 2 n-tiles x 16 kk = 128 VGPRs
    short8 bf0[16], bf1[16];
    {
        const int nb = wv * 32;
        const int swz = c7 << 3;
#pragma unroll
        for (int kk = 0; kk < 16; ++kk) {
            int kb = (kk * 32 + kgrp * 8) ^ swz;
            bf0[kk] = *(const short8*)&Rlds[(nb + cB) * 512 + kb];
            bf1[kk] = *(const short8*)&Rlds[(nb + 16 + cB) * 512 + kb];
        }
    }
    __syncthreads();

    // ---- stage w slice [n=128][k=256] bf16 (hi only), swizzled; reuse Rlds ----
    for (int e = tid; e < 64 * 256; e += 256) {
        int p = e & 63, k = e >> 6;
        int n0 = 2 * p;
        int loc = n0 & 31, w = n0 >> 5;
        int gate = ((loc >> 4) << 1) | ((loc >> 3) & 1);
        int gcol = gate * Hh + hc0 + w * 8 + (loc & 7);
        float2 v = *(const float2*)(kern + (size_t)k * G4 + gcol);
        Rlds[n0 * 256 + (k ^ ((n0 & 7) << 3))] = f2bf(v.x);
        Rlds[(n0 + 1) * 256 + (k ^ (((n0 + 1) & 7) << 3))] = f2bf(v.y);
    }
    __syncthreads();
    // hoist w fragments: 2 n-tiles x 8 kk = 64 VGPRs
    short8 wf0[8], wf1[8];
    {
        const int nb = wv * 32;
        const int swz = c7 << 3;
#pragma unroll
        for (int kk = 0; kk < 8; ++kk) {
            int kb = (kk * 32 + kgrp * 8) ^ swz;
            wf0[kk] = *(const short8*)&Rlds[(nb + cB) * 256 + kb];
            wf1[kk] = *(const short8*)&Rlds[(nb + 16 + cB) * 256 + kb];
        }
    }
    // bias scalars for this lane's col
    const float bi = bias[0 * Hh + col], bff = bias[1 * Hh + col];
    const float bg = bias[2 * Hh + col], bo = bias[3 * Hh + col];
    __syncthreads();   // w-hoist reads done; Rlds free for h/x buffers

    // ---- stage x(0) into x buf0 ----
    {
        float xf[16];
        const float* xp = x + ((size_t)(b0 + xrow) * Tt + 0) * Ff + xkq * 16;
#pragma unroll
        for (int j = 0; j < 4; ++j) *(float4*)(&xf[4 * j]) = ((const float4*)xp)[j];
        xconv_write(xf, Rlds + XB, xrow, xkq);
    }
    __syncthreads();

    float creg[4] = {0.f, 0.f, 0.f, 0.f};
    unsigned* const gbase = hbuf_u + (size_t)rg * 4 * 4096;   // 4 slots x 16x256 dwords
    const bool ew = (!hi && !(cB & 1));
    const int swz = c7 << 3;

    for (int t = 0; t < Tt; ++t) {
        const bool last = (t == Tt - 1);

        // B. x(t+1) loads: issued FIRST (pre-poll -> drain free during spin)
        float xf[16];
        if (!last) {
            const float* xp = x + ((size_t)(b0 + xrow) * Tt + (t + 1)) * Ff + xkq * 16;
#pragma unroll
            for (int j = 0; j < 4; ++j) *(float4*)(&xf[4 * j]) = ((const float4*)xp)[j];
        }

        // A. xz-GEMM(t): x_lds[t&1] (split hi/lo) @ w-frags. Independent of the
        //    recurrence -> its MFMA+ds_read latency overlaps the poll spin.
        floatx4 xza0 = (floatx4){0.f, 0.f, 0.f, 0.f};
        floatx4 xza1 = (floatx4){0.f, 0.f, 0.f, 0.f};
        {
            const unsigned short* xb = Rlds + XB + (t & 1) * 8192;
#pragma unroll
            for (int kk = 0; kk < 8; ++kk) {
                int kb = (kk * 32 + kgrp * 8) ^ swz;
                short8 ah = *(const short8*)&xb[cB * 256 + kb];
                short8 al = *(const short8*)&xb[4096 + cB * 256 + kb];
                xza0 = __builtin_amdgcn_mfma_f32_16x16x32_bf16(ah, wf0[kk], xza0, 0, 0, 0);
                xza0 = __builtin_amdgcn_mfma_f32_16x16x32_bf16(al, wf0[kk], xza0, 0, 0, 0);
                xza1 = __builtin_amdgcn_mfma_f32_16x16x32_bf16(ah, wf1[kk], xza1, 0, 0, 0);
                xza1 = __builtin_amdgcn_mfma_f32_16x16x32_bf16(al, wf1[kk], xza1, 0, 0, 0);
            }
        }

        floatx4 acc0 = (floatx4){0.f, 0.f, 0.f, 0.f};
        floatx4 acc1 = (floatx4){0.f, 0.f, 0.f, 0.f};
        unsigned short* const hst = Rlds + ((t & 1) ? 8192 : 0);   // h buf parity
        unsigned* const hcu = (unsigned*)hst;

        if (t > 0) {
            // C. poll+stage h(t-1) from slot (t-1)&3 (R6 verbatim: per-row retry)
            const unsigned* sb = gbase + ((t - 1) & 3) * 4096;
            const unsigned* q0 = sb + (wv + 0) * 256 + 4 * lane;
            const unsigned* q1 = sb + (wv + 4) * 256 + 4 * lane;
            const unsigned* q2 = sb + (wv + 8) * 256 + 4 * lane;
            const unsigned* q3 = sb + (wv + 12) * 256 + 4 * lane;
            uint4v v0, v1, v2, v3;
            asm volatile("global_load_dwordx4 %0, %1, off sc0 sc1" : "=v"(v0) : "v"(q0) : "memory");
            asm volatile("global_load_dwordx4 %0, %1, off sc0 sc1" : "=v"(v1) : "v"(q1) : "memory");
            asm volatile("global_load_dwordx4 %0, %1, off sc0 sc1" : "=v"(v2) : "v"(q2) : "memory");
            asm volatile("global_load_dwordx4 %0, %1, off sc0 sc1" : "=v"(v3) : "v"(q3) : "memory");
            asm volatile("s_waitcnt vmcnt(0)" ::: "memory");
            while (__any((v0[0] == SENT) | (v0[1] == SENT) | (v0[2] == SENT) | (v0[3] == SENT))) {
                asm volatile("global_load_dwordx4 %0, %1, off sc0 sc1" : "=v"(v0) : "v"(q0) : "memory");
                asm volatile("s_waitcnt vmcnt(0)" ::: "memory");
            }
            *(uint4v*)(hcu + (wv + 0) * 256 + 4 * (lane ^ ((wv + 0) & 7))) = v0;
            while (__any((v1[0] == SENT) | (v1[1] == SENT) | (v1[2] == SENT) | (v1[3] == SENT))) {
                asm volatile("global_load_dwordx4 %0, %1, off sc0 sc1" : "=v"(v1) : "v"(q1) : "memory");
                asm volatile("s_waitcnt vmcnt(0)" ::: "memory");
            }
            *(uint4v*)(hcu + (wv + 4) * 256 + 4 * (lane ^ ((wv + 4) & 7))) = v1;
            while (__any((v2[0] == SENT) | (v2[1] == SENT) | (v2[2] == SENT) | (v2[3] == SENT))) {
                asm volatile("global_load_dwordx4 %0, %1, off sc0 sc1" : "=v"(v2) : "v"(q2) : "memory");
                asm volatile("s_waitcnt vmcnt(0)" ::: "memory");
            }
            *(uint4v*)(hcu + (wv + 8) * 256 + 4 * (lane ^ ((wv + 8) & 7))) = v2;
            while (__any((v3[0] == SENT) | (v3[1] == SENT) | (v3[2] == SENT) | (v3[3] == SENT))) {
                asm volatile("global_load_dwordx4 %0, %1, off sc0 sc1" : "=v"(v3) : "v"(q3) : "memory");
                asm volatile("s_waitcnt vmcnt(0)" ::: "memory");
            }
            *(uint4v*)(hcu + (wv + 12) * 256 + 4 * (lane ^ ((wv + 12) & 7))) = v3;

            // D. recycle slot (t-2) (fire-and-forget; drained at next poll)
            if (t >= 2) {
                unsigned* rs = gbase + ((t - 2) & 3) * 4096
                             + (tid >> 4) * 256 + (hc0 >> 1) + (tid & 15);
                __hip_atomic_store(rs, SENT, __ATOMIC_RELAXED, __HIP_MEMORY_SCOPE_AGENT);
            }
        }

        // I. convert + write x(t+1) into x buf (t+1)&1 (before the barrier so
        //    next iter's phase A can read it; loads already drained by poll)
        if (!last)
            xconv_write(xf, Rlds + XB + ((t + 1) & 1) * 8192, xrow, xkq);

        __syncthreads();   // one barrier/step: h tile + x tile visible to all

        // F. h-GEMM: 16 ds_read_b128 + 32 MFMA (dual chains), B-frags in regs
        if (t > 0) {
            floatx4 e0 = (floatx4){0.f, 0.f, 0.f, 0.f};
            floatx4 e1 = (floatx4){0.f, 0.f, 0.f, 0.f};
#pragma unroll
            for (int kk = 0; kk < 16; kk += 2) {
                int kb0 = (kk * 32 + kgrp * 8) ^ swz;
                int kb1 = ((kk + 1) * 32 + kgrp * 8) ^ swz;
                short8 a0 = *(const short8*)&hst[cB * 512 + kb0];
                short8 a1 = *(const short8*)&hst[cB * 512 + kb1];
                acc0 = __builtin_amdgcn_mfma_f32_16x16x32_bf16(a0, bf0[kk], acc0, 0, 0, 0);
                acc1 = __builtin_amdgcn_mfma_f32_16x16x32_bf16(a0, bf1[kk], acc1, 0, 0, 0);
                e0 = __builtin_amdgcn_mfma_f32_16x16x32_bf16(a1, bf0[kk + 1], e0, 0, 0, 0);
                e1 = __builtin_amdgcn_mfma_f32_16x16x32_bf16(a1, bf1[kk + 1], e1, 0, 0, 0);
            }
            acc0 = acc0 + e0;
            acc1 = acc1 + e1;
        }

        // G. elementwise: z = sel(h_acc + xz_acc) + bias. C layout col=lane&15,
        //    row=kgrp*4+r; tile0=[i|f], tile1=[g|o]; shfl_xor(8) pairs gates.
        floatx4 s0 = acc0 + xza0;
        floatx4 s1 = acc1 + xza1;
        float hv[4];
#pragma unroll
        for (int r = 0; r < 4; ++r) {
            float f0 = s0[r], f1 = s1[r];
            float f0x = __shfl_xor(f0, 8);
            float f1x = __shfl_xor(f1, 8);
            float zi = (hi ? f0x : f0) + bi;
            float zf = (hi ? f0 : f0x) + bff;
            float zg = (hi ? f1x : f1) + bg;
            float zo = (hi ? f1 : f1x) + bo;
            creg[r] = sigm(zf) * creg[r] + sigm(zi) * tanh_f(zg);
            hv[r] = sigm(zo) * tanh_f(creg[r]);
        }

        float hn[4];
#pragma unroll
        for (int r = 0; r < 4; ++r) hn[r] = __shfl_xor(hv[r], 1);

        if (!last) {
            // H. h exchange (critical path) then out stores; both drained at the
            //    next poll while spinning on producers (R6-winning placement).
            unsigned* wbase = gbase + (t & 3) * 4096;
#pragma unroll
            for (int r = 0; r < 4; ++r) {
                if (ew) {
                    unsigned hp = (unsigned)f2bf(hv[r]) | ((unsigned)f2bf(hn[r]) << 16);
                    __hip_atomic_store(wbase + (kgrp * 4 + r) * 256 + (col >> 1), hp,
                                       __ATOMIC_RELAXED, __HIP_MEMORY_SCOPE_AGENT);
                }
            }
#pragma unroll
            for (int r = 0; r < 4; ++r) {
                if (ew) {
                    size_t b = (size_t)(b0 + kgrp * 4 + r);
                    *(float2*)(out + (b * Tt + (size_t)t) * Hh + col) = make_float2(hv[r], hn[r]);
                }
            }
        } else {
            float* hl = out + (size_t)Bb * Tt * Hh;
            float* cl = hl + (size_t)Bb * Hh;
#pragma unroll
            for (int r = 0; r < 4; ++r) {
                float cn = __shfl_xor(creg[r], 1);
                if (ew) {
                    size_t b = (size_t)(b0 + kgrp * 4 + r);
                    *(float2*)(out + (b * Tt + (size_t)t) * Hh + col) = make_float2(hv[r], hn[r]);
                    *(float2*)(hl + b * Hh + col) = make_float2(hv[r], hn[r]);
                    *(float2*)(cl + b * Hh + col) = make_float2(creg[r], cn);
                }
            }
            break;
        }
    }
}

// ---------------------------------------------------------------------------
extern "C" void kernel_launch(void* const* d_in, const int* in_sizes, int n_in,
                              void* d_out, int out_size, void* d_ws, size_t ws_size,
                              hipStream_t stream) {
    (void)in_sizes; (void)n_in; (void)out_size; (void)ws_size;
    const float* x    = (const float*)d_in[0];
    const float* w    = (const float*)d_in[1];
    const float* rk   = (const float*)d_in[2];
    const float* bias = (const float*)d_in[3];
    float* out = (float*)d_out;

    const size_t HBUF_BYTES = (size_t)8 * 4 * 16 * 256 * 4;   // 524,288
    unsigned* hbuf = (unsigned*)d_ws;

    // sentinel-init all slots (0xFF bytes -> 0xFFFFFFFF dwords)
    hipMemsetAsync(d_ws, 0xFF, HBUF_BYTES, stream);

    lstm_rec<<<dim3(128), dim3(256), 0, stream>>>(x, w, rk, bias, hbuf, out);
}